// Round 13
// baseline (329.928 us; speedup 1.0000x reference)
//
#include <hip/hip_runtime.h>
#include <hip/hip_bf16.h>
#include <hip/hip_cooperative_groups.h>

namespace cg = cooperative_groups;

#define C_DIM 320
#define N_DIM 4096
#define NEG 0.01f

typedef float f32x4 __attribute__((ext_vector_type(4)));
typedef float f32x2 __attribute__((ext_vector_type(2)));
typedef short bf16x8 __attribute__((ext_vector_type(8)));
typedef __bf16 bfv8 __attribute__((ext_vector_type(8)));

__device__ __forceinline__ float lrelu(float e) { return fmaxf(e, NEG * e); }

__device__ __forceinline__ unsigned short bf16bits(float v) {
    __hip_bfloat16 h = __float2bfloat16(v);
    return *(unsigned short*)&h;
}
__device__ __forceinline__ float bf16tof(unsigned short u) {
    unsigned int bits = ((unsigned int)u) << 16;
    return __builtin_bit_cast(float, bits);
}

__device__ __forceinline__ void gload_lds16(const void* g, void* l) {
    __builtin_amdgcn_global_load_lds(
        (const __attribute__((address_space(1))) void*)g,
        (__attribute__((address_space(3))) void*)l, 16, 0, 0);
}

// strict left-assoc fold of 5 c-group partials; IDENTICAL everywhere so sort
// keys and tie-breaks are byte-identical.
__device__ __forceinline__ float fold5(const float* __restrict__ p, int b, int i) {
    float v = p[((size_t)(b * 5 + 0)) * N_DIM + i];
    v += p[((size_t)(b * 5 + 1)) * N_DIM + i];
    v += p[((size_t)(b * 5 + 2)) * N_DIM + i];
    v += p[((size_t)(b * 5 + 3)) * N_DIM + i];
    v += p[((size_t)(b * 5 + 4)) * N_DIM + i];
    return v;
}

// ============================================================
// Sorted-prefix algorithm (no GEMM), single cooperative kernel:
// phase1 pre -> phase2 rank -> phase3 scatter -> phase4 prefix||jz -> phase5 out
// grid.sync() between phases (replaces 4 dispatch boundaries).
// ============================================================

__global__ __launch_bounds__(256, 3) void k_mega(
        const float* __restrict__ x, const float* __restrict__ W,
        float* __restrict__ s1p, float* __restrict__ s2p,
        short* __restrict__ xT, int* __restrict__ pcnt,
        float* __restrict__ Sg, int* __restrict__ idxg,
        float* __restrict__ Eg, float* __restrict__ Gg,
        int* __restrict__ JnA, float* __restrict__ fzA, float* __restrict__ hzA,
        unsigned int* __restrict__ Tloc, float* __restrict__ tot,
        float* __restrict__ out) {
    cg::grid_group grid = cg::this_grid();
    __shared__ union {
        struct { float tile[64][65]; float r1[4][64]; float r2[4][64]; } pre;
        struct { float ch[512]; } rk;
        struct { float Sl[4096]; float Ei[4096]; float Gi[4096];
                 float wsE[4]; float wsG[4]; } jz;
        struct { float offl[65][64][2]; float wsum[4][64][2]; float tile[64][65]; } op;
    } sm;
    const int bid = blockIdx.x;
    const int tid = threadIdx.x;
    const int w = tid >> 6, l = tid & 63;

    // ---------------- phase 1: pre (all 640 blocks) ----------------
    {
        const int nb = bid % 64, cgi = (bid >> 6) % 5, b = bid / 320;
        const int n0 = nb * 64, c0 = cgi * 64;
        const int n = n0 + l;
        float a1 = 0.f, a2 = 0.f;
        #pragma unroll
        for (int cc = 0; cc < 16; ++cc) {
            const int cl = w * 16 + cc;
            const int c = c0 + cl;
            float v = x[((size_t)(b * C_DIM + c)) * N_DIM + n];
            a1 = fmaf(v, W[c], a1);
            a2 = fmaf(v, W[C_DIM + c], a2);
            sm.pre.tile[cl][l] = v;
        }
        sm.pre.r1[w][l] = a1; sm.pre.r2[w][l] = a2;
        __syncthreads();
        const int half = l >> 5, cp = l & 31;
        #pragma unroll
        for (int rr = 0; rr < 8; ++rr) {
            const int nr = w * 16 + rr * 2 + half;
            unsigned int pk = (unsigned int)bf16bits(sm.pre.tile[2 * cp][nr])
                            | ((unsigned int)bf16bits(sm.pre.tile[2 * cp + 1][nr]) << 16);
            *(unsigned int*)&xT[((size_t)b * N_DIM + n0 + nr) * C_DIM + c0 + 2 * cp] = pk;
        }
        if (tid < 64) {
            float t1 = sm.pre.r1[0][l] + sm.pre.r1[1][l] + sm.pre.r1[2][l] + sm.pre.r1[3][l];
            float t2 = sm.pre.r2[0][l] + sm.pre.r2[1][l] + sm.pre.r2[2][l] + sm.pre.r2[3][l];
            s1p[((size_t)(b * 5 + cgi)) * N_DIM + n] = t1;
            s2p[((size_t)(b * 5 + cgi)) * N_DIM + n] = t2;
        }
    }
    grid.sync();

    // ---------------- phase 2: rank (256 blocks) ----------------
    if (bid < 256) {
        const int chunk = bid & 7, kt = (bid >> 3) & 15, b = bid >> 7;
        const int kbase = chunk * 512;
        sm.rk.ch[tid] = fold5(s1p, b, kbase + tid);
        sm.rk.ch[tid + 256] = fold5(s1p, b, kbase + tid + 256);
        __syncthreads();
        const int k = kt * 256 + tid;
        const float v = fold5(s1p, b, k);
        int cnt = 0;
        #pragma unroll 8
        for (int i = 0; i < 512; ++i) {
            float sv = sm.rk.ch[i];
            int kc = kbase + i;
            cnt += (sv < v || (sv == v && kc < k)) ? 1 : 0;
        }
        pcnt[(b * 8 + chunk) * N_DIM + k] = cnt;
    }
    grid.sync();

    // ---------------- phase 3: scatter (32 blocks) ----------------
    if (bid < 32) {
        const int b = bid >> 4;
        const int k = (bid & 15) * 256 + tid;
        int r = 0;
        #pragma unroll
        for (int c = 0; c < 8; ++c) r += pcnt[(b * 8 + c) * N_DIM + k];
        const float v = fold5(s1p, b, k);
        Sg[b * N_DIM + r] = v;
        idxg[b * N_DIM + r] = k;
        Eg[b * N_DIM + r] = __expf(v);
        Gg[b * N_DIM + r] = __expf(NEG * v);
    }
    grid.sync();

    // ---------------- phase 4: prefix (160) || jz (32) ----------------
    if (bid < 160) {
        const int jt4 = bid & 15;
        const int cgi = (bid >> 4) % 5;
        const int b = bid / 80;
        const int tile = jt4 * 4 + w;
        const int jbase = tile * 64;
        const int c = cgi * 64 + l;
        const short* xTb = xT + (size_t)b * N_DIM * C_DIM;
        const float ej = Eg[b * N_DIM + jbase + l];
        const float gj = Gg[b * N_DIM + jbase + l];
        const int   ij = idxg[b * N_DIM + jbase + l];
        float se = 0.f, sg = 0.f;
        #pragma unroll
        for (int hb = 0; hb < 2; ++hb) {
            // batch-load 32 gathers, then compute (32-deep MLP, VGPR-safe)
            unsigned short xv[32];
            #pragma unroll
            for (int j = 0; j < 32; ++j) {
                const int kidx = __shfl(ij, hb * 32 + j);
                xv[j] = (unsigned short)xTb[(size_t)kidx * C_DIM + c];
            }
            #pragma unroll
            for (int j = 0; j < 32; ++j) {
                const float e = __shfl(ej, hb * 32 + j);
                const float g = __shfl(gj, hb * 32 + j);
                const float x0 = bf16tof(xv[j]);
                se = fmaf(x0, e, se);
                sg = fmaf(x0, g, sg);
                Tloc[((size_t)b * N_DIM + jbase + hb * 32 + j) * C_DIM + c] =
                    (unsigned int)bf16bits(se) | ((unsigned int)bf16bits(sg) << 16);
            }
        }
        *(f32x2*)&tot[(((size_t)b * 64 + tile) * C_DIM + c) * 2] = (f32x2){se, sg};
    } else if (bid < 192) {
        const int jb = bid - 160;           // 0..31
        const int b = jb >> 4;
        const int nbase = (jb & 15) * 256;
        for (int i = tid; i < 4096; i += 256) sm.jz.Sl[i] = Sg[b * N_DIM + i];
        float pe[16], pg[16];
        float se = 0.f, sgg = 0.f;
        #pragma unroll
        for (int q = 0; q < 4; ++q) {
            f32x4 e4 = *(const f32x4*)&Eg[b * N_DIM + tid * 16 + q * 4];
            f32x4 g4 = *(const f32x4*)&Gg[b * N_DIM + tid * 16 + q * 4];
            #pragma unroll
            for (int j = 0; j < 4; ++j) {
                se += e4[j];  pe[q * 4 + j] = se;
                sgg += g4[j]; pg[q * 4 + j] = sgg;
            }
        }
        float ie = se, ig = sgg;
        #pragma unroll
        for (int o = 1; o < 64; o <<= 1) {
            float ue = __shfl_up(ie, o);
            float ug = __shfl_up(ig, o);
            if (l >= o) { ie += ue; ig += ug; }
        }
        if (l == 63) { sm.jz.wsE[w] = ie; sm.jz.wsG[w] = ig; }
        __syncthreads();
        float oe = 0.f, og = 0.f;
        for (int ww = 0; ww < w; ++ww) { oe += sm.jz.wsE[ww]; og += sm.jz.wsG[ww]; }
        const float baseE = oe + ie - se, baseG = og + ig - sgg;
        #pragma unroll
        for (int q = 0; q < 16; ++q) {
            sm.jz.Ei[tid * 16 + q] = baseE + pe[q];
            sm.jz.Gi[tid * 16 + q] = baseG + pg[q];
        }
        __syncthreads();
        const float EPt = sm.jz.Ei[4095];
        const float smax = sm.jz.Sl[4095];
        const int n = nbase + tid;
        const float s2n = fold5(s2p, b, n);
        const float mn = lrelu(s2n + smax);
        const float F = __expf(s2n - mn), H = __expf(NEG * s2n - mn);
        const float t = -s2n;
        int lo = 0, hi = 4096;
        while (lo < hi) {
            int mid = (lo + hi) >> 1;
            if (sm.jz.Sl[mid] < t) lo = mid + 1; else hi = mid;
        }
        const float EPlo = lo ? sm.jz.Ei[lo - 1] : 0.f;
        const float GPlo = lo ? sm.jz.Gi[lo - 1] : 0.f;
        const float rz = 1.f / (F * (EPt - EPlo) + H * GPlo);
        JnA[b * N_DIM + n] = lo;
        fzA[b * N_DIM + n] = F * rz;
        hzA[b * N_DIM + n] = H * rz;
    }
    grid.sync();

    // ---------------- phase 5: out (all 640 blocks) ----------------
    {
        const int nb = bid % 64, cgi = (bid >> 6) % 5, b = bid / 320;
        const int n0 = nb * 64, c0 = cgi * 64;
        float ae = 0.f, ag = 0.f;
        #pragma unroll
        for (int i = 0; i < 16; ++i) {
            const int jt = w * 16 + i;
            sm.op.offl[jt][l][0] = ae; sm.op.offl[jt][l][1] = ag;
            f32x2 v = *(const f32x2*)&tot[(((size_t)b * 64 + jt) * C_DIM + c0 + l) * 2];
            ae += v[0]; ag += v[1];
        }
        sm.op.wsum[w][l][0] = ae; sm.op.wsum[w][l][1] = ag;
        __syncthreads();
        float be = 0.f, bg = 0.f;
        for (int ww = 0; ww < w; ++ww) { be += sm.op.wsum[ww][l][0]; bg += sm.op.wsum[ww][l][1]; }
        #pragma unroll
        for (int i = 0; i < 16; ++i) {
            const int jt = w * 16 + i;
            sm.op.offl[jt][l][0] += be; sm.op.offl[jt][l][1] += bg;
        }
        if (w == 3) { sm.op.offl[64][l][0] = be + ae; sm.op.offl[64][l][1] = bg + ag; }
        __syncthreads();

        const float gtE = sm.op.offl[64][l][0];

        #pragma unroll
        for (int half = 0; half < 2; ++half) {
            unsigned int tvp[8];
            f32x2 ov[8];
            float fzs[8], hzs[8], msk[8];
            #pragma unroll
            for (int i = 0; i < 8; ++i) {
                const int n = n0 + w * 16 + half * 8 + i;
                const int Jn = JnA[b * N_DIM + n];
                fzs[i] = fzA[b * N_DIM + n];
                hzs[i] = hzA[b * N_DIM + n];
                const int jt = Jn >> 6, jl = Jn & 63;
                msk[i] = jl ? 1.f : 0.f;
                const int jrow = jl ? (Jn - 1) : 0;
                ov[i][0] = sm.op.offl[jt][l][0];
                ov[i][1] = sm.op.offl[jt][l][1];
                tvp[i] = Tloc[((size_t)b * N_DIM + jrow) * C_DIM + c0 + l];
            }
            #pragma unroll
            for (int i = 0; i < 8; ++i) {
                const float tvE = bf16tof((unsigned short)(tvp[i] & 0xFFFFu));
                const float tvG = bf16tof((unsigned short)(tvp[i] >> 16));
                const float se_ex = ov[i][0] + msk[i] * tvE;
                const float sg_ex = ov[i][1] + msk[i] * tvG;
                sm.op.tile[l][w * 16 + half * 8 + i] = fzs[i] * (gtE - se_ex) + hzs[i] * sg_ex;
            }
        }
        __syncthreads();
        const int row = tid >> 2, nseg = (tid & 3) * 16;
        const size_t gidx = ((size_t)(b * C_DIM + c0 + row)) * N_DIM + n0 + nseg;
        #pragma unroll
        for (int i2 = 0; i2 < 16; i2 += 4) {
            f32x4 xv = *(const f32x4*)&x[gidx + i2];
            f32x4 o;
            #pragma unroll
            for (int q = 0; q < 4; ++q) o[q] = sm.op.tile[row][nseg + i2 + q] + xv[q];
            *(f32x4*)&out[gidx + i2] = o;
        }
    }
}

// ============================================================
// R12 5-dispatch path (proven 47.5 us) — fallback if coop launch fails
// ============================================================

__global__ __launch_bounds__(256) void k_pre(const float* __restrict__ x,
                                             const float* __restrict__ W,
                                             float* __restrict__ s1p,
                                             float* __restrict__ s2p,
                                             short* __restrict__ xT) {
    __shared__ float tile[64][65];
    __shared__ float r1[4][64], r2[4][64];
    const int b = blockIdx.z, cg2 = blockIdx.y, nb = blockIdx.x;
    const int nl = threadIdx.x & 63, cw = threadIdx.x >> 6;
    const int n0 = nb * 64, c0 = cg2 * 64;
    const int n = n0 + nl;
    float a1 = 0.f, a2 = 0.f;
    #pragma unroll
    for (int cc = 0; cc < 16; ++cc) {
        const int cl = cw * 16 + cc;
        const int c = c0 + cl;
        float v = x[((size_t)(b * C_DIM + c)) * N_DIM + n];
        a1 = fmaf(v, W[c], a1);
        a2 = fmaf(v, W[C_DIM + c], a2);
        tile[cl][nl] = v;
    }
    r1[cw][nl] = a1; r2[cw][nl] = a2;
    __syncthreads();
    const int half = nl >> 5;
    const int cp = nl & 31;
    #pragma unroll
    for (int rr = 0; rr < 8; ++rr) {
        const int nr = cw * 16 + rr * 2 + half;
        unsigned int pk = (unsigned int)bf16bits(tile[2 * cp][nr])
                        | ((unsigned int)bf16bits(tile[2 * cp + 1][nr]) << 16);
        *(unsigned int*)&xT[((size_t)b * N_DIM + n0 + nr) * C_DIM + c0 + 2 * cp] = pk;
    }
    if (threadIdx.x < 64) {
        float t1 = r1[0][nl] + r1[1][nl] + r1[2][nl] + r1[3][nl];
        float t2 = r2[0][nl] + r2[1][nl] + r2[2][nl] + r2[3][nl];
        s1p[((size_t)(b * 5 + cg2)) * N_DIM + n] = t1;
        s2p[((size_t)(b * 5 + cg2)) * N_DIM + n] = t2;
    }
}

__global__ __launch_bounds__(256) void k_rank(const float* __restrict__ s1p,
                                              int* __restrict__ pcnt) {
    __shared__ float ch[512];
    const int chunk = blockIdx.x, kt = blockIdx.y, b = blockIdx.z;
    const int tid = threadIdx.x;
    const int kbase = chunk * 512;
    ch[tid] = fold5(s1p, b, kbase + tid);
    ch[tid + 256] = fold5(s1p, b, kbase + tid + 256);
    __syncthreads();
    const int k = kt * 256 + tid;
    const float v = fold5(s1p, b, k);
    int cnt = 0;
    #pragma unroll 8
    for (int i = 0; i < 512; ++i) {
        float sv = ch[i];
        int kc = kbase + i;
        cnt += (sv < v || (sv == v && kc < k)) ? 1 : 0;
    }
    pcnt[(b * 8 + chunk) * N_DIM + k] = cnt;
}

__global__ __launch_bounds__(256) void k_sct(const float* __restrict__ s1p,
                                             const int* __restrict__ pcnt,
                                             float* __restrict__ Sg,
                                             int* __restrict__ idxg,
                                             float* __restrict__ Eg,
                                             float* __restrict__ Gg) {
    const int b = blockIdx.y;
    const int k = blockIdx.x * 256 + threadIdx.x;
    int r = 0;
    #pragma unroll
    for (int c = 0; c < 8; ++c) r += pcnt[(b * 8 + c) * N_DIM + k];
    const float v = fold5(s1p, b, k);
    Sg[b * N_DIM + r] = v;
    idxg[b * N_DIM + r] = k;
    Eg[b * N_DIM + r] = __expf(v);
    Gg[b * N_DIM + r] = __expf(NEG * v);
}

__global__ __launch_bounds__(256) void k_pjz(const short* __restrict__ xT,
                                             const int* __restrict__ idxg,
                                             const float* __restrict__ Eg,
                                             const float* __restrict__ Gg,
                                             const float* __restrict__ Sg,
                                             const float* __restrict__ s2p,
                                             unsigned int* __restrict__ Tloc,
                                             float* __restrict__ tot,
                                             int* __restrict__ JnA,
                                             float* __restrict__ fzA,
                                             float* __restrict__ hzA) {
    __shared__ float Sl[4096];
    __shared__ float Ei[4096], Gi[4096];
    __shared__ float wsE[4], wsG[4];
    const int w = threadIdx.x >> 6, l = threadIdx.x & 63;
    const int bx = blockIdx.x;
    if (bx < 160) {
        const int jt4 = bx & 15;
        const int cg2 = (bx >> 4) % 5;
        const int b = bx / 80;
        const int tile = jt4 * 4 + w;
        const int jbase = tile * 64;
        const int c = cg2 * 64 + l;
        const short* xTb = xT + (size_t)b * N_DIM * C_DIM;
        const float ej = Eg[b * N_DIM + jbase + l];
        const float gj = Gg[b * N_DIM + jbase + l];
        const int   ij = idxg[b * N_DIM + jbase + l];
        unsigned short xv[64];
        #pragma unroll
        for (int j = 0; j < 64; ++j) {
            const int kidx = __shfl(ij, j);
            xv[j] = (unsigned short)xTb[(size_t)kidx * C_DIM + c];
        }
        float se = 0.f, sg = 0.f;
        #pragma unroll
        for (int j = 0; j < 64; ++j) {
            const float e = __shfl(ej, j);
            const float g = __shfl(gj, j);
            const float x0 = bf16tof(xv[j]);
            se = fmaf(x0, e, se);
            sg = fmaf(x0, g, sg);
            Tloc[((size_t)b * N_DIM + jbase + j) * C_DIM + c] =
                (unsigned int)bf16bits(se) | ((unsigned int)bf16bits(sg) << 16);
        }
        *(f32x2*)&tot[(((size_t)b * 64 + tile) * C_DIM + c) * 2] = (f32x2){se, sg};
    } else {
        const int jb = bx - 160;
        const int b = jb >> 4;
        const int nbase = (jb & 15) * 256;
        const int tid = threadIdx.x;
        for (int i = tid; i < 4096; i += 256) Sl[i] = Sg[b * N_DIM + i];
        float pe[16], pg[16];
        float se = 0.f, sgg = 0.f;
        #pragma unroll
        for (int q = 0; q < 4; ++q) {
            f32x4 e4 = *(const f32x4*)&Eg[b * N_DIM + tid * 16 + q * 4];
            f32x4 g4 = *(const f32x4*)&Gg[b * N_DIM + tid * 16 + q * 4];
            #pragma unroll
            for (int j = 0; j < 4; ++j) {
                se += e4[j];  pe[q * 4 + j] = se;
                sgg += g4[j]; pg[q * 4 + j] = sgg;
            }
        }
        float ie = se, ig = sgg;
        #pragma unroll
        for (int o = 1; o < 64; o <<= 1) {
            float ue = __shfl_up(ie, o);
            float ug = __shfl_up(ig, o);
            if (l >= o) { ie += ue; ig += ug; }
        }
        if (l == 63) { wsE[w] = ie; wsG[w] = ig; }
        __syncthreads();
        float oe = 0.f, og = 0.f;
        for (int ww = 0; ww < w; ++ww) { oe += wsE[ww]; og += wsG[ww]; }
        const float baseE = oe + ie - se, baseG = og + ig - sgg;
        #pragma unroll
        for (int q = 0; q < 16; ++q) {
            Ei[tid * 16 + q] = baseE + pe[q];
            Gi[tid * 16 + q] = baseG + pg[q];
        }
        __syncthreads();
        const float EPt = Ei[4095];
        const float smax = Sl[4095];
        const int n = nbase + tid;
        const float s2n = fold5(s2p, b, n);
        const float mn = lrelu(s2n + smax);
        const float F = __expf(s2n - mn), H = __expf(NEG * s2n - mn);
        const float t = -s2n;
        int lo = 0, hi = 4096;
        while (lo < hi) {
            int mid = (lo + hi) >> 1;
            if (Sl[mid] < t) lo = mid + 1; else hi = mid;
        }
        const float EPlo = lo ? Ei[lo - 1] : 0.f;
        const float GPlo = lo ? Gi[lo - 1] : 0.f;
        const float rz = 1.f / (F * (EPt - EPlo) + H * GPlo);
        JnA[b * N_DIM + n] = lo;
        fzA[b * N_DIM + n] = F * rz;
        hzA[b * N_DIM + n] = H * rz;
    }
}

__global__ __launch_bounds__(256) void k_out(const float* __restrict__ x,
                                             const unsigned int* __restrict__ Tloc,
                                             const float* __restrict__ tot,
                                             const int* __restrict__ JnA,
                                             const float* __restrict__ fzA,
                                             const float* __restrict__ hzA,
                                             float* __restrict__ out) {
    __shared__ float offl[65][64][2];
    __shared__ float wsum[4][64][2];
    __shared__ float tile[64][65];
    const int b = blockIdx.z, cg2 = blockIdx.y, n0 = blockIdx.x * 64;
    const int tid = threadIdx.x, w = tid >> 6, l = tid & 63;
    const int c0 = cg2 * 64;

    float ae = 0.f, ag = 0.f;
    #pragma unroll
    for (int i = 0; i < 16; ++i) {
        const int jt = w * 16 + i;
        offl[jt][l][0] = ae; offl[jt][l][1] = ag;
        f32x2 v = *(const f32x2*)&tot[(((size_t)b * 64 + jt) * C_DIM + c0 + l) * 2];
        ae += v[0]; ag += v[1];
    }
    wsum[w][l][0] = ae; wsum[w][l][1] = ag;
    __syncthreads();
    float be = 0.f, bg = 0.f;
    for (int ww = 0; ww < w; ++ww) { be += wsum[ww][l][0]; bg += wsum[ww][l][1]; }
    #pragma unroll
    for (int i = 0; i < 16; ++i) {
        const int jt = w * 16 + i;
        offl[jt][l][0] += be; offl[jt][l][1] += bg;
    }
    if (w == 3) { offl[64][l][0] = be + ae; offl[64][l][1] = bg + ag; }
    __syncthreads();

    const float gtE = offl[64][l][0];

    #pragma unroll
    for (int half = 0; half < 2; ++half) {
        unsigned int tvp[8];
        f32x2 ov[8];
        float fzs[8], hzs[8], msk[8];
        #pragma unroll
        for (int i = 0; i < 8; ++i) {
            const int n = n0 + w * 16 + half * 8 + i;
            const int Jn = JnA[b * N_DIM + n];
            fzs[i] = fzA[b * N_DIM + n];
            hzs[i] = hzA[b * N_DIM + n];
            const int jt = Jn >> 6, jl = Jn & 63;
            msk[i] = jl ? 1.f : 0.f;
            const int jrow = jl ? (Jn - 1) : 0;
            ov[i][0] = offl[jt][l][0];
            ov[i][1] = offl[jt][l][1];
            tvp[i] = Tloc[((size_t)b * N_DIM + jrow) * C_DIM + c0 + l];
        }
        #pragma unroll
        for (int i = 0; i < 8; ++i) {
            const float tvE = bf16tof((unsigned short)(tvp[i] & 0xFFFFu));
            const float tvG = bf16tof((unsigned short)(tvp[i] >> 16));
            const float se_ex = ov[i][0] + msk[i] * tvE;
            const float sg_ex = ov[i][1] + msk[i] * tvG;
            tile[l][w * 16 + half * 8 + i] = fzs[i] * (gtE - se_ex) + hzs[i] * sg_ex;
        }
    }
    __syncthreads();
    const int row = tid >> 2, nseg = (tid & 3) * 16;
    const size_t gidx = ((size_t)(b * C_DIM + c0 + row)) * N_DIM + n0 + nseg;
    #pragma unroll
    for (int i2 = 0; i2 < 16; i2 += 4) {
        f32x4 xv = *(const f32x4*)&x[gidx + i2];
        f32x4 o;
        #pragma unroll
        for (int q = 0; q < 4; ++q) o[q] = tile[row][nseg + i2 + q] + xv[q];
        *(f32x4*)&out[gidx + i2] = o;
    }
}

// ============================================================
// MID fallback: round-3 path (proven 75 us)
// ============================================================

__global__ __launch_bounds__(256) void k_s12(const float* __restrict__ x,
                                             const float* __restrict__ W,
                                             float* __restrict__ s1p,
                                             float* __restrict__ s2p,
                                             short* __restrict__ xb) {
    const int b = blockIdx.z, cb = blockIdx.y;
    const int nl = threadIdx.x & 63, cw = threadIdx.x >> 6;
    const int n = blockIdx.x * 64 + nl;
    const int cbase = cb * 64 + cw * 16;
    const float* px = x + ((size_t)b * C_DIM + cbase) * N_DIM + n;
    short* pxb = xb + ((size_t)b * C_DIM + cbase) * N_DIM + n;
    const float* w1 = W + cbase;
    const float* w2 = W + C_DIM + cbase;
    float a1 = 0.f, a2 = 0.f;
    #pragma unroll
    for (int cc = 0; cc < 16; ++cc) {
        float v = px[(size_t)cc * N_DIM];
        a1 = fmaf(v, w1[cc], a1);
        a2 = fmaf(v, w2[cc], a2);
        __hip_bfloat16 hv = __float2bfloat16(v);
        pxb[(size_t)cc * N_DIM] = *(short*)&hv;
    }
    __shared__ float r1[4][64], r2[4][64];
    r1[cw][nl] = a1; r2[cw][nl] = a2;
    __syncthreads();
    if (threadIdx.x < 64) {
        s1p[((size_t)b * 5 + cb) * N_DIM + n] = r1[0][nl] + r1[1][nl] + r1[2][nl] + r1[3][nl];
        s2p[((size_t)b * 5 + cb) * N_DIM + n] = r2[0][nl] + r2[1][nl] + r2[2][nl] + r2[3][nl];
    }
}

__global__ __launch_bounds__(1024) void k_fold(const float* __restrict__ s1p,
                                               const float* __restrict__ s2p,
                                               float* __restrict__ s2,
                                               float* __restrict__ Ekf,
                                               float* __restrict__ Gkf,
                                               float* __restrict__ s1max) {
    const int b = blockIdx.x, tid = threadIdx.x;
    __shared__ float md[1024];
    float mx = -3.4e38f;
    for (int n = tid; n < N_DIM; n += 1024) {
        float v1 = 0.f, v2 = 0.f;
        #pragma unroll
        for (int cb = 0; cb < 5; ++cb) {
            v1 += s1p[((size_t)b * 5 + cb) * N_DIM + n];
            v2 += s2p[((size_t)b * 5 + cb) * N_DIM + n];
        }
        s2[b * N_DIM + n] = v2;
        Ekf[b * N_DIM + n] = __expf(v1);
        Gkf[b * N_DIM + n] = __expf(NEG * v1);
        mx = fmaxf(mx, v1);
    }
    md[tid] = mx;
    __syncthreads();
    for (int s = 512; s > 0; s >>= 1) {
        if (tid < s) md[tid] = fmaxf(md[tid], md[tid + s]);
        __syncthreads();
    }
    if (tid == 0) s1max[b] = md[0];
}

__global__ __launch_bounds__(256) void k_z(const float* __restrict__ s2,
                                           const float* __restrict__ s1max,
                                           const float* __restrict__ Ekf,
                                           const float* __restrict__ Gkf,
                                           float* __restrict__ Fz,
                                           float* __restrict__ Hz) {
    __shared__ __align__(16) float Els[4096], Gls[4096];
    const int b = blockIdx.y, tid = threadIdx.x;
    const int w = tid >> 6, l = tid & 63;
    const float* Eb = Ekf + b * N_DIM;
    const float* Gb = Gkf + b * N_DIM;
    #pragma unroll
    for (int i = 0; i < 4; ++i) {
        int chn = i * 256 + tid;
        *(f32x4*)&Els[chn * 4] = *(const f32x4*)&Eb[chn * 4];
        *(f32x4*)&Gls[chn * 4] = *(const f32x4*)&Gb[chn * 4];
    }
    __syncthreads();
    float smax = s1max[b];
    #pragma unroll
    for (int rr = 0; rr < 4; ++rr) {
        int row = b * N_DIM + blockIdx.x * 16 + w * 4 + rr;
        float s2n = s2[row];
        float mn = lrelu(s2n + smax);
        float F = __expf(s2n - mn), H = __expf(NEG * s2n - mn);
        float sum = 0.f;
        #pragma unroll 4
        for (int i = 0; i < 16; ++i) {
            int k = i * 256 + l * 4;
            f32x4 e = *(const f32x4*)&Els[k];
            f32x4 gg = *(const f32x4*)&Gls[k];
            #pragma unroll
            for (int j = 0; j < 4; ++j) sum += fmaxf(e[j] * F, gg[j] * H);
        }
        #pragma unroll
        for (int off = 32; off > 0; off >>= 1) sum += __shfl_down(sum, off);
        if (l == 0) {
            float rz = 1.f / sum;
            Fz[row] = F * rz;
            Hz[row] = H * rz;
        }
    }
}

__global__ __launch_bounds__(128) void k_gemm(const short* __restrict__ xb,
                                              const float* __restrict__ x,
                                              const float* __restrict__ Ekf,
                                              const float* __restrict__ Gkf,
                                              const float* __restrict__ Fz,
                                              const float* __restrict__ Hz,
                                              float* __restrict__ out) {
    __shared__ __align__(16) short Asm[2][2][4096];
    __shared__ __align__(16) float EGs[2][2][256];

    const int b = blockIdx.z, c0 = blockIdx.y * 64, n0 = blockIdx.x * 64;
    const int tid = threadIdx.x;
    const int h = tid >> 6, l = tid & 63, lr = l & 15, g = l >> 4;
    const short* xbp = xb + (size_t)b * C_DIM * N_DIM + h * 2048;
    const float* Eb = Ekf + b * N_DIM + h * 2048;
    const float* Gb = Gkf + b * N_DIM + h * 2048;

    int ncol[4]; float fz[4], hz[4];
    #pragma unroll
    for (int t = 0; t < 4; ++t) {
        int n = n0 + t * 16 + lr;
        ncol[t] = n;
        fz[t] = Fz[b * N_DIM + n];
        hz[t] = Hz[b * N_DIM + n];
    }

    f32x4 acc[4][4];
    #pragma unroll
    for (int i = 0; i < 4; ++i)
        #pragma unroll
        for (int t = 0; t < 4; ++t) acc[i][t] = (f32x4){0.f, 0.f, 0.f, 0.f};

    auto stageA = [&](int buf, int it) {
        #pragma unroll
        for (int i = 0; i < 8; ++i) {
            int row = i * 8 + (l >> 3);
            int c8 = (l & 7) ^ (row & 7);
            gload_lds16(xbp + (size_t)(c0 + row) * N_DIM + it * 64 + c8 * 8,
                        &Asm[h][buf][i * 512]);
        }
    };
    auto stageEG = [&](int buf, int it) {
        int lm = l & 31;
        const float* p = (lm < 16) ? (Eb + it * 64 + lm * 4)
                                   : (Gb + it * 64 + (lm - 16) * 4);
        gload_lds16(p, &EGs[h][buf][0]);
    };

    stageA(0, 0); stageEG(0, 0);
    for (int it = 0; it < 32; ++it) {
        const int buf = it & 1;
        if (it < 31) {
            stageA(buf ^ 1, it + 1);
            stageEG(buf ^ 1, it + 1);
            asm volatile("s_waitcnt vmcnt(9)" ::: "memory");
        } else {
            asm volatile("s_waitcnt vmcnt(0)" ::: "memory");
        }
        __builtin_amdgcn_sched_barrier(0);
        #pragma unroll
        for (int s = 0; s < 2; ++s) {
            const int kk = s * 32 + g * 8;
            f32x4 e0 = *(const f32x4*)&EGs[h][buf][kk];
            f32x4 e1 = *(const f32x4*)&EGs[h][buf][kk + 4];
            f32x4 g0 = *(const f32x4*)&EGs[h][buf][64 + kk];
            f32x4 g1 = *(const f32x4*)&EGs[h][buf][64 + kk + 4];
            bf16x8 afr[4];
            #pragma unroll
            for (int i = 0; i < 4; ++i) {
                int row = 16 * i + lr;
                int idx = row * 64 + (((4 * s + g) ^ (row & 7)) * 8);
                afr[i] = *(const bf16x8*)&Asm[h][buf][idx];
            }
            bf16x8 bfr[4];
            #pragma unroll
            for (int t = 0; t < 4; ++t) {
                bfv8 qv;
                #pragma unroll
                for (int j = 0; j < 4; ++j) {
                    qv[j]     = (__bf16)fmaxf(e0[j] * fz[t], g0[j] * hz[t]);
                    qv[j + 4] = (__bf16)fmaxf(e1[j] * fz[t], g1[j] * hz[t]);
                }
                bfr[t] = __builtin_bit_cast(bf16x8, qv);
            }
            #pragma unroll
            for (int i = 0; i < 4; ++i)
                #pragma unroll
                for (int t = 0; t < 4; ++t)
                    acc[i][t] = __builtin_amdgcn_mfma_f32_16x16x32_bf16(
                        afr[i], bfr[t], acc[i][t], 0, 0, 0);
        }
    }

    __syncthreads();
    float* red = (float*)&Asm[0][0][0];
    if (h == 1) {
        #pragma unroll
        for (int i = 0; i < 4; ++i)
            #pragma unroll
            for (int t = 0; t < 4; ++t)
                #pragma unroll
                for (int r = 0; r < 4; ++r)
                    red[((i * 4 + t) * 4 + r) * 64 + l] = acc[i][t][r];
    }
    __syncthreads();
    if (h == 0) {
        #pragma unroll
        for (int i = 0; i < 4; ++i)
            #pragma unroll
            for (int t = 0; t < 4; ++t)
                #pragma unroll
                for (int r = 0; r < 4; ++r) {
                    float v = acc[i][t][r] + red[((i * 4 + t) * 4 + r) * 64 + l];
                    int c = c0 + 16 * i + g * 4 + r;
                    size_t idx = ((size_t)(b * C_DIM + c)) * N_DIM + ncol[t];
                    out[idx] = v + x[idx];
                }
    }
}

// ============================================================
// launch
// ============================================================

extern "C" void kernel_launch(void* const* d_in, const int* in_sizes, int n_in,
                              void* d_out, int out_size, void* d_ws, size_t ws_size,
                              hipStream_t stream) {
    const float* x = (const float*)d_in[0];
    const float* W = (const float*)d_in[1];
    float* out = (float*)d_out;
    float* ws = (float*)d_ws;

    // ---- new-path ws layout (float offsets) ----
    const size_t o_s1p = 0,           // 40960
                 o_s2p = 40960,       // 40960
                 o_S   = 81920,       // 8192
                 o_idx = 90112,       // 8192
                 o_Eg  = 98304,       // 8192
                 o_Gg  = 106496,      // 8192
                 o_Jn  = 131076,      // 8192
                 o_fz  = 139268,      // 8192
                 o_hz  = 147460,      // 8192
                 o_pc  = 155652,      // 65536
                 o_tot = 221188,      // 81920
                 o_xT  = 303108,      // 1310720 (bf16 2*4096*320)
                 o_Tl  = 1613828,     // 2621440 (u32 2*4096*320)
                 o_end = 4235268;
    const size_t need_new = o_end * 4;

    // ---- mid-path (round-3) ws layout ----
    const size_t m_s1p = 0, m_s2p = 40960, m_s2 = 81920, m_Ek = 90112,
                 m_Gk = 98304, m_Fz = 106496, m_Hz = 114688, m_mx = 122880,
                 m_xb = 122888;
    const size_t need_mid = m_xb * 4 + (size_t)2 * C_DIM * N_DIM * 2;

    if (ws_size >= need_new) {
        float* s1p = ws + o_s1p;
        float* s2p = ws + o_s2p;
        float* Sg = ws + o_S;
        int*   idxg = (int*)(ws + o_idx);
        float* Eg = ws + o_Eg;
        float* Gg = ws + o_Gg;
        int*   JnA = (int*)(ws + o_Jn);
        float* fzA = ws + o_fz;
        float* hzA = ws + o_hz;
        int*   pcnt = (int*)(ws + o_pc);
        float* tot = ws + o_tot;
        short* xT = (short*)(ws + o_xT);
        unsigned int* Tloc = (unsigned int*)(ws + o_Tl);

        void* args[] = { (void*)&x, (void*)&W, (void*)&s1p, (void*)&s2p,
                         (void*)&xT, (void*)&pcnt, (void*)&Sg, (void*)&idxg,
                         (void*)&Eg, (void*)&Gg, (void*)&JnA, (void*)&fzA,
                         (void*)&hzA, (void*)&Tloc, (void*)&tot, (void*)&out };
        hipError_t err = hipLaunchCooperativeKernel(
            (const void*)k_mega, dim3(640), dim3(256), args, 0, stream);
        if (err != hipSuccess) {
            (void)hipGetLastError();  // clear sticky error, use 5-dispatch path
            k_pre <<<dim3(64, 5, 2), 256, 0, stream>>>(x, W, s1p, s2p, xT);
            k_rank<<<dim3(8, 16, 2), 256, 0, stream>>>(s1p, pcnt);
            k_sct <<<dim3(16, 2), 256, 0, stream>>>(s1p, pcnt, Sg, idxg, Eg, Gg);
            k_pjz <<<192, 256, 0, stream>>>(xT, idxg, Eg, Gg, Sg, s2p,
                                            Tloc, tot, JnA, fzA, hzA);
            k_out <<<dim3(64, 5, 2), 256, 0, stream>>>(x, Tloc, tot, JnA, fzA, hzA, out);
        }
    } else {
        float* s1p = ws + m_s1p;
        float* s2p = ws + m_s2p;
        float* s2  = ws + m_s2;
        float* Ekf = ws + m_Ek;
        float* Gkf = ws + m_Gk;
        float* Fz  = ws + m_Fz;
        float* Hz  = ws + m_Hz;
        float* s1max = ws + m_mx;
        short* xb = (short*)(ws + m_xb);
        k_s12 <<<dim3(64, 5, 2), 256, 0, stream>>>(x, W, s1p, s2p, xb);
        k_fold<<<2, 1024, 0, stream>>>(s1p, s2p, s2, Ekf, Gkf, s1max);
        k_z   <<<dim3(256, 2), 256, 0, stream>>>(s2, s1max, Ekf, Gkf, Fz, Hz);
        k_gemm<<<dim3(64, 5, 2), 128, 0, stream>>>(xb, x, Ekf, Gkf, Fz, Hz, out);
    }
}

// Round 14
// 70.013 us; speedup vs baseline: 4.7124x; 4.7124x over previous
//
#include <hip/hip_runtime.h>
#include <hip/hip_bf16.h>

#define C_DIM 320
#define N_DIM 4096
#define NEG 0.01f

typedef float f32x4 __attribute__((ext_vector_type(4)));
typedef float f32x2 __attribute__((ext_vector_type(2)));
typedef short bf16x8 __attribute__((ext_vector_type(8)));
typedef __bf16 bfv8 __attribute__((ext_vector_type(8)));

__device__ __forceinline__ float lrelu(float e) { return fmaxf(e, NEG * e); }

__device__ __forceinline__ unsigned short bf16bits(float v) {
    __hip_bfloat16 h = __float2bfloat16(v);
    return *(unsigned short*)&h;
}
__device__ __forceinline__ float bf16tof(unsigned short u) {
    unsigned int bits = ((unsigned int)u) << 16;
    return __builtin_bit_cast(float, bits);
}

__device__ __forceinline__ void gload_lds16(const void* g, void* l) {
    __builtin_amdgcn_global_load_lds(
        (const __attribute__((address_space(1))) void*)g,
        (__attribute__((address_space(3))) void*)l, 16, 0, 0);
}

// strict left-assoc fold of 5 c-group partials; IDENTICAL everywhere so sort
// keys and tie-breaks are byte-identical.
__device__ __forceinline__ float fold5(const float* __restrict__ p, int b, int i) {
    float v = p[((size_t)(b * 5 + 0)) * N_DIM + i];
    v += p[((size_t)(b * 5 + 1)) * N_DIM + i];
    v += p[((size_t)(b * 5 + 2)) * N_DIM + i];
    v += p[((size_t)(b * 5 + 3)) * N_DIM + i];
    v += p[((size_t)(b * 5 + 4)) * N_DIM + i];
    return v;
}

// ============================================================
// Sorted-prefix algorithm (no GEMM):
// out[c,n] = fz[n]*(SEtot[c] - SE_ex(Jn)[c]) + hz[n]*SG_ex(Jn)[c] + P[c,n]
// k sorted ascending by s1; Jn = lower_bound(S, -s2[n]).
// 4 dispatches: pre -> rs(rank+scatter) -> pjz(prefix || jz) -> out(+scan)
// ============================================================

// per (nb, cg, b): partial s1/s2 over 64 c's + bf16 transpose of 64n x 64c tile
__global__ __launch_bounds__(256) void k_pre(const float* __restrict__ x,
                                             const float* __restrict__ W,
                                             float* __restrict__ s1p,
                                             float* __restrict__ s2p,
                                             short* __restrict__ xT) {
    __shared__ float tile[64][65];
    __shared__ float r1[4][64], r2[4][64];
    const int b = blockIdx.z, cg = blockIdx.y, nb = blockIdx.x;
    const int nl = threadIdx.x & 63, cw = threadIdx.x >> 6;
    const int n0 = nb * 64, c0 = cg * 64;
    const int n = n0 + nl;
    float a1 = 0.f, a2 = 0.f;
    #pragma unroll
    for (int cc = 0; cc < 16; ++cc) {
        const int cl = cw * 16 + cc;
        const int c = c0 + cl;
        float v = x[((size_t)(b * C_DIM + c)) * N_DIM + n];
        a1 = fmaf(v, W[c], a1);
        a2 = fmaf(v, W[C_DIM + c], a2);
        tile[cl][nl] = v;
    }
    r1[cw][nl] = a1; r2[cw][nl] = a2;
    __syncthreads();
    const int half = nl >> 5;
    const int cp = nl & 31;
    #pragma unroll
    for (int rr = 0; rr < 8; ++rr) {
        const int nr = cw * 16 + rr * 2 + half;
        unsigned int pk = (unsigned int)bf16bits(tile[2 * cp][nr])
                        | ((unsigned int)bf16bits(tile[2 * cp + 1][nr]) << 16);
        *(unsigned int*)&xT[((size_t)b * N_DIM + n0 + nr) * C_DIM + c0 + 2 * cp] = pk;
    }
    if (threadIdx.x < 64) {
        float t1 = r1[0][nl] + r1[1][nl] + r1[2][nl] + r1[3][nl];
        float t2 = r2[0][nl] + r2[1][nl] + r2[2][nl] + r2[3][nl];
        s1p[((size_t)(b * 5 + cg)) * N_DIM + n] = t1;
        s2p[((size_t)(b * 5 + cg)) * N_DIM + n] = t2;
    }
}

// fused rank+scatter: 256 blocks. Each block stages full fold5(s1) in LDS,
// ranks 32 k's (8 threads/k, 512-elem chunks each, staggered to avoid bank
// conflicts), reduces via shfl(width=8), scatters sorted arrays directly.
__global__ __launch_bounds__(256) void k_rs(const float* __restrict__ s1p,
                                            float* __restrict__ Sg,
                                            int* __restrict__ idxg,
                                            float* __restrict__ Eg,
                                            float* __restrict__ Gg) {
    __shared__ float Sl[4096];
    const int b = blockIdx.y, kb = blockIdx.x;   // kb in 0..127
    const int tid = threadIdx.x;
    #pragma unroll
    for (int q = 0; q < 16; ++q) {
        const int i = q * 256 + tid;
        Sl[i] = fold5(s1p, b, i);
    }
    __syncthreads();
    const int k = kb * 32 + (tid >> 3);
    const int seg = tid & 7;
    const float v = Sl[k];
    int cnt = 0;
    const int base = seg * 512;
    const int rot = seg * 68;                    // 68%32=4 -> distinct banks
    #pragma unroll 8
    for (int i = 0; i < 512; ++i) {
        const int off = (i + rot) & 511;
        const int idx = base + off;
        const float sv = Sl[idx];
        cnt += (sv < v || (sv == v && idx < k)) ? 1 : 0;
    }
    cnt += __shfl_down(cnt, 4, 8);
    cnt += __shfl_down(cnt, 2, 8);
    cnt += __shfl_down(cnt, 1, 8);
    if (seg == 0) {
        const int r = cnt;
        Sg[b * N_DIM + r] = v;
        idxg[b * N_DIM + r] = k;
        Eg[b * N_DIM + r] = __expf(v);
        Gg[b * N_DIM + r] = __expf(NEG * v);
    }
}

// fused dispatch: blocks 0..159 = prefix (load-all-64 then compute, max MLP);
// blocks 160..191 = jz: stage sorted S/E/G, build EP/GP prefix in LDS (scan),
// then binary-search + Z for 256 rows each. Runs on CUs idle during prefix.
__global__ __launch_bounds__(256) void k_pjz(const short* __restrict__ xT,
                                             const int* __restrict__ idxg,
                                             const float* __restrict__ Eg,
                                             const float* __restrict__ Gg,
                                             const float* __restrict__ Sg,
                                             const float* __restrict__ s2p,
                                             unsigned int* __restrict__ Tloc,
                                             float* __restrict__ tot,
                                             int* __restrict__ JnA,
                                             float* __restrict__ fzA,
                                             float* __restrict__ hzA) {
    __shared__ float Sl[4096];
    __shared__ float Ei[4096], Gi[4096];
    __shared__ float wsE[4], wsG[4];
    const int w = threadIdx.x >> 6, l = threadIdx.x & 63;
    const int bx = blockIdx.x;
    if (bx < 160) {
        const int jt4 = bx & 15;
        const int cg = (bx >> 4) % 5;
        const int b = bx / 80;
        const int tile = jt4 * 4 + w;
        const int jbase = tile * 64;
        const int c = cg * 64 + l;
        const short* xTb = xT + (size_t)b * N_DIM * C_DIM;
        const float ej = Eg[b * N_DIM + jbase + l];
        const float gj = Gg[b * N_DIM + jbase + l];
        const int   ij = idxg[b * N_DIM + jbase + l];
        // phase 1: issue ALL 64 gathers (wave-limited occupancy; VGPRs free)
        unsigned short xv[64];
        #pragma unroll
        for (int j = 0; j < 64; ++j) {
            const int kidx = __shfl(ij, j);
            xv[j] = (unsigned short)xTb[(size_t)kidx * C_DIM + c];
        }
        // phase 2: prefix + packed stores, zero gather stalls
        float se = 0.f, sg = 0.f;
        #pragma unroll
        for (int j = 0; j < 64; ++j) {
            const float e = __shfl(ej, j);
            const float g = __shfl(gj, j);
            const float x0 = bf16tof(xv[j]);
            se = fmaf(x0, e, se);
            sg = fmaf(x0, g, sg);
            Tloc[((size_t)b * N_DIM + jbase + j) * C_DIM + c] =
                (unsigned int)bf16bits(se) | ((unsigned int)bf16bits(sg) << 16);
        }
        *(f32x2*)&tot[(((size_t)b * 64 + tile) * C_DIM + c) * 2] = (f32x2){se, sg};
    } else {
        const int jb = bx - 160;            // 0..31
        const int b = jb >> 4;
        const int nbase = (jb & 15) * 256;
        const int tid = threadIdx.x;
        for (int i = tid; i < 4096; i += 256) Sl[i] = Sg[b * N_DIM + i];
        float pe[16], pg[16];
        float se = 0.f, sgg = 0.f;
        #pragma unroll
        for (int q = 0; q < 4; ++q) {
            f32x4 e4 = *(const f32x4*)&Eg[b * N_DIM + tid * 16 + q * 4];
            f32x4 g4 = *(const f32x4*)&Gg[b * N_DIM + tid * 16 + q * 4];
            #pragma unroll
            for (int j = 0; j < 4; ++j) {
                se += e4[j];  pe[q * 4 + j] = se;
                sgg += g4[j]; pg[q * 4 + j] = sgg;
            }
        }
        float ie = se, ig = sgg;
        #pragma unroll
        for (int o = 1; o < 64; o <<= 1) {
            float ue = __shfl_up(ie, o);
            float ug = __shfl_up(ig, o);
            if (l >= o) { ie += ue; ig += ug; }
        }
        if (l == 63) { wsE[w] = ie; wsG[w] = ig; }
        __syncthreads();
        float oe = 0.f, og = 0.f;
        for (int ww = 0; ww < w; ++ww) { oe += wsE[ww]; og += wsG[ww]; }
        const float baseE = oe + ie - se, baseG = og + ig - sgg;
        #pragma unroll
        for (int q = 0; q < 16; ++q) {
            Ei[tid * 16 + q] = baseE + pe[q];
            Gi[tid * 16 + q] = baseG + pg[q];
        }
        __syncthreads();
        const float EPt = Ei[4095];
        const float smax = Sl[4095];
        const int n = nbase + tid;
        const float s2n = fold5(s2p, b, n);
        const float mn = lrelu(s2n + smax);
        const float F = __expf(s2n - mn), H = __expf(NEG * s2n - mn);
        const float t = -s2n;
        int lo = 0, hi = 4096;
        while (lo < hi) {
            int mid = (lo + hi) >> 1;
            if (Sl[mid] < t) lo = mid + 1; else hi = mid;
        }
        const float EPlo = lo ? Ei[lo - 1] : 0.f;
        const float GPlo = lo ? Gi[lo - 1] : 0.f;
        const float rz = 1.f / (F * (EPt - EPlo) + H * GPlo);
        JnA[b * N_DIM + n] = lo;
        fzA[b * N_DIM + n] = F * rz;
        hzA[b * N_DIM + n] = H * rz;
    }
}

// fused: per-block tile-offset scan + lookup + transpose + residual
__global__ __launch_bounds__(256) void k_out(const float* __restrict__ x,
                                             const unsigned int* __restrict__ Tloc,
                                             const float* __restrict__ tot,
                                             const int* __restrict__ JnA,
                                             const float* __restrict__ fzA,
                                             const float* __restrict__ hzA,
                                             float* __restrict__ out) {
    __shared__ float offl[65][64][2];
    __shared__ float wsum[4][64][2];
    __shared__ float tile[64][65];
    const int b = blockIdx.z, cg = blockIdx.y, n0 = blockIdx.x * 64;
    const int tid = threadIdx.x, w = tid >> 6, l = tid & 63;
    const int c0 = cg * 64;

    float ae = 0.f, ag = 0.f;
    #pragma unroll
    for (int i = 0; i < 16; ++i) {
        const int jt = w * 16 + i;
        offl[jt][l][0] = ae; offl[jt][l][1] = ag;
        f32x2 v = *(const f32x2*)&tot[(((size_t)b * 64 + jt) * C_DIM + c0 + l) * 2];
        ae += v[0]; ag += v[1];
    }
    wsum[w][l][0] = ae; wsum[w][l][1] = ag;
    __syncthreads();
    float be = 0.f, bg = 0.f;
    for (int ww = 0; ww < w; ++ww) { be += wsum[ww][l][0]; bg += wsum[ww][l][1]; }
    #pragma unroll
    for (int i = 0; i < 16; ++i) {
        const int jt = w * 16 + i;
        offl[jt][l][0] += be; offl[jt][l][1] += bg;
    }
    if (w == 3) { offl[64][l][0] = be + ae; offl[64][l][1] = bg + ag; }
    __syncthreads();

    const float gtE = offl[64][l][0];

    #pragma unroll
    for (int half = 0; half < 2; ++half) {
        unsigned int tvp[8];
        f32x2 ov[8];
        float fzs[8], hzs[8], msk[8];
        #pragma unroll
        for (int i = 0; i < 8; ++i) {
            const int n = n0 + w * 16 + half * 8 + i;
            const int Jn = JnA[b * N_DIM + n];
            fzs[i] = fzA[b * N_DIM + n];
            hzs[i] = hzA[b * N_DIM + n];
            const int jt = Jn >> 6, jl = Jn & 63;
            msk[i] = jl ? 1.f : 0.f;
            const int jrow = jl ? (Jn - 1) : 0;
            ov[i][0] = offl[jt][l][0];
            ov[i][1] = offl[jt][l][1];
            tvp[i] = Tloc[((size_t)b * N_DIM + jrow) * C_DIM + c0 + l];
        }
        #pragma unroll
        for (int i = 0; i < 8; ++i) {
            const float tvE = bf16tof((unsigned short)(tvp[i] & 0xFFFFu));
            const float tvG = bf16tof((unsigned short)(tvp[i] >> 16));
            const float se_ex = ov[i][0] + msk[i] * tvE;
            const float sg_ex = ov[i][1] + msk[i] * tvG;
            tile[l][w * 16 + half * 8 + i] = fzs[i] * (gtE - se_ex) + hzs[i] * sg_ex;
        }
    }
    __syncthreads();
    const int row = tid >> 2, nseg = (tid & 3) * 16;
    const size_t gidx = ((size_t)(b * C_DIM + c0 + row)) * N_DIM + n0 + nseg;
    #pragma unroll
    for (int i2 = 0; i2 < 16; i2 += 4) {
        f32x4 xv = *(const f32x4*)&x[gidx + i2];
        f32x4 o;
        #pragma unroll
        for (int q = 0; q < 4; ++q) o[q] = tile[row][nseg + i2 + q] + xv[q];
        *(f32x4*)&out[gidx + i2] = o;
    }
}

// ============================================================
// MID fallback: round-3 path (proven 75 us)
// ============================================================

__global__ __launch_bounds__(256) void k_s12(const float* __restrict__ x,
                                             const float* __restrict__ W,
                                             float* __restrict__ s1p,
                                             float* __restrict__ s2p,
                                             short* __restrict__ xb) {
    const int b = blockIdx.z, cb = blockIdx.y;
    const int nl = threadIdx.x & 63, cw = threadIdx.x >> 6;
    const int n = blockIdx.x * 64 + nl;
    const int cbase = cb * 64 + cw * 16;
    const float* px = x + ((size_t)b * C_DIM + cbase) * N_DIM + n;
    short* pxb = xb + ((size_t)b * C_DIM + cbase) * N_DIM + n;
    const float* w1 = W + cbase;
    const float* w2 = W + C_DIM + cbase;
    float a1 = 0.f, a2 = 0.f;
    #pragma unroll
    for (int cc = 0; cc < 16; ++cc) {
        float v = px[(size_t)cc * N_DIM];
        a1 = fmaf(v, w1[cc], a1);
        a2 = fmaf(v, w2[cc], a2);
        __hip_bfloat16 hv = __float2bfloat16(v);
        pxb[(size_t)cc * N_DIM] = *(short*)&hv;
    }
    __shared__ float r1[4][64], r2[4][64];
    r1[cw][nl] = a1; r2[cw][nl] = a2;
    __syncthreads();
    if (threadIdx.x < 64) {
        s1p[((size_t)b * 5 + cb) * N_DIM + n] = r1[0][nl] + r1[1][nl] + r1[2][nl] + r1[3][nl];
        s2p[((size_t)b * 5 + cb) * N_DIM + n] = r2[0][nl] + r2[1][nl] + r2[2][nl] + r2[3][nl];
    }
}

__global__ __launch_bounds__(1024) void k_fold(const float* __restrict__ s1p,
                                               const float* __restrict__ s2p,
                                               float* __restrict__ s2,
                                               float* __restrict__ Ekf,
                                               float* __restrict__ Gkf,
                                               float* __restrict__ s1max) {
    const int b = blockIdx.x, tid = threadIdx.x;
    __shared__ float md[1024];
    float mx = -3.4e38f;
    for (int n = tid; n < N_DIM; n += 1024) {
        float v1 = 0.f, v2 = 0.f;
        #pragma unroll
        for (int cb = 0; cb < 5; ++cb) {
            v1 += s1p[((size_t)b * 5 + cb) * N_DIM + n];
            v2 += s2p[((size_t)b * 5 + cb) * N_DIM + n];
        }
        s2[b * N_DIM + n] = v2;
        Ekf[b * N_DIM + n] = __expf(v1);
        Gkf[b * N_DIM + n] = __expf(NEG * v1);
        mx = fmaxf(mx, v1);
    }
    md[tid] = mx;
    __syncthreads();
    for (int s = 512; s > 0; s >>= 1) {
        if (tid < s) md[tid] = fmaxf(md[tid], md[tid + s]);
        __syncthreads();
    }
    if (tid == 0) s1max[b] = md[0];
}

__global__ __launch_bounds__(256) void k_z(const float* __restrict__ s2,
                                           const float* __restrict__ s1max,
                                           const float* __restrict__ Ekf,
                                           const float* __restrict__ Gkf,
                                           float* __restrict__ Fz,
                                           float* __restrict__ Hz) {
    __shared__ __align__(16) float Els[4096], Gls[4096];
    const int b = blockIdx.y, tid = threadIdx.x;
    const int w = tid >> 6, l = tid & 63;
    const float* Eb = Ekf + b * N_DIM;
    const float* Gb = Gkf + b * N_DIM;
    #pragma unroll
    for (int i = 0; i < 4; ++i) {
        int chn = i * 256 + tid;
        *(f32x4*)&Els[chn * 4] = *(const f32x4*)&Eb[chn * 4];
        *(f32x4*)&Gls[chn * 4] = *(const f32x4*)&Gb[chn * 4];
    }
    __syncthreads();
    float smax = s1max[b];
    #pragma unroll
    for (int rr = 0; rr < 4; ++rr) {
        int row = b * N_DIM + blockIdx.x * 16 + w * 4 + rr;
        float s2n = s2[row];
        float mn = lrelu(s2n + smax);
        float F = __expf(s2n - mn), H = __expf(NEG * s2n - mn);
        float sum = 0.f;
        #pragma unroll 4
        for (int i = 0; i < 16; ++i) {
            int k = i * 256 + l * 4;
            f32x4 e = *(const f32x4*)&Els[k];
            f32x4 gg = *(const f32x4*)&Gls[k];
            #pragma unroll
            for (int j = 0; j < 4; ++j) sum += fmaxf(e[j] * F, gg[j] * H);
        }
        #pragma unroll
        for (int off = 32; off > 0; off >>= 1) sum += __shfl_down(sum, off);
        if (l == 0) {
            float rz = 1.f / sum;
            Fz[row] = F * rz;
            Hz[row] = H * rz;
        }
    }
}

__global__ __launch_bounds__(128) void k_gemm(const short* __restrict__ xb,
                                              const float* __restrict__ x,
                                              const float* __restrict__ Ekf,
                                              const float* __restrict__ Gkf,
                                              const float* __restrict__ Fz,
                                              const float* __restrict__ Hz,
                                              float* __restrict__ out) {
    __shared__ __align__(16) short Asm[2][2][4096];
    __shared__ __align__(16) float EGs[2][2][256];

    const int b = blockIdx.z, c0 = blockIdx.y * 64, n0 = blockIdx.x * 64;
    const int tid = threadIdx.x;
    const int h = tid >> 6, l = tid & 63, lr = l & 15, g = l >> 4;
    const short* xbp = xb + (size_t)b * C_DIM * N_DIM + h * 2048;
    const float* Eb = Ekf + b * N_DIM + h * 2048;
    const float* Gb = Gkf + b * N_DIM + h * 2048;

    int ncol[4]; float fz[4], hz[4];
    #pragma unroll
    for (int t = 0; t < 4; ++t) {
        int n = n0 + t * 16 + lr;
        ncol[t] = n;
        fz[t] = Fz[b * N_DIM + n];
        hz[t] = Hz[b * N_DIM + n];
    }

    f32x4 acc[4][4];
    #pragma unroll
    for (int i = 0; i < 4; ++i)
        #pragma unroll
        for (int t = 0; t < 4; ++t) acc[i][t] = (f32x4){0.f, 0.f, 0.f, 0.f};

    auto stageA = [&](int buf, int it) {
        #pragma unroll
        for (int i = 0; i < 8; ++i) {
            int row = i * 8 + (l >> 3);
            int c8 = (l & 7) ^ (row & 7);
            gload_lds16(xbp + (size_t)(c0 + row) * N_DIM + it * 64 + c8 * 8,
                        &Asm[h][buf][i * 512]);
        }
    };
    auto stageEG = [&](int buf, int it) {
        int lm = l & 31;
        const float* p = (lm < 16) ? (Eb + it * 64 + lm * 4)
                                   : (Gb + it * 64 + (lm - 16) * 4);
        gload_lds16(p, &EGs[h][buf][0]);
    };

    stageA(0, 0); stageEG(0, 0);
    for (int it = 0; it < 32; ++it) {
        const int buf = it & 1;
        if (it < 31) {
            stageA(buf ^ 1, it + 1);
            stageEG(buf ^ 1, it + 1);
            asm volatile("s_waitcnt vmcnt(9)" ::: "memory");
        } else {
            asm volatile("s_waitcnt vmcnt(0)" ::: "memory");
        }
        __builtin_amdgcn_sched_barrier(0);
        #pragma unroll
        for (int s = 0; s < 2; ++s) {
            const int kk = s * 32 + g * 8;
            f32x4 e0 = *(const f32x4*)&EGs[h][buf][kk];
            f32x4 e1 = *(const f32x4*)&EGs[h][buf][kk + 4];
            f32x4 g0 = *(const f32x4*)&EGs[h][buf][64 + kk];
            f32x4 g1 = *(const f32x4*)&EGs[h][buf][64 + kk + 4];
            bf16x8 afr[4];
            #pragma unroll
            for (int i = 0; i < 4; ++i) {
                int row = 16 * i + lr;
                int idx = row * 64 + (((4 * s + g) ^ (row & 7)) * 8);
                afr[i] = *(const bf16x8*)&Asm[h][buf][idx];
            }
            bf16x8 bfr[4];
            #pragma unroll
            for (int t = 0; t < 4; ++t) {
                bfv8 qv;
                #pragma unroll
                for (int j = 0; j < 4; ++j) {
                    qv[j]     = (__bf16)fmaxf(e0[j] * fz[t], g0[j] * hz[t]);
                    qv[j + 4] = (__bf16)fmaxf(e1[j] * fz[t], g1[j] * hz[t]);
                }
                bfr[t] = __builtin_bit_cast(bf16x8, qv);
            }
            #pragma unroll
            for (int i = 0; i < 4; ++i)
                #pragma unroll
                for (int t = 0; t < 4; ++t)
                    acc[i][t] = __builtin_amdgcn_mfma_f32_16x16x32_bf16(
                        afr[i], bfr[t], acc[i][t], 0, 0, 0);
        }
    }

    __syncthreads();
    float* red = (float*)&Asm[0][0][0];
    if (h == 1) {
        #pragma unroll
        for (int i = 0; i < 4; ++i)
            #pragma unroll
            for (int t = 0; t < 4; ++t)
                #pragma unroll
                for (int r = 0; r < 4; ++r)
                    red[((i * 4 + t) * 4 + r) * 64 + l] = acc[i][t][r];
    }
    __syncthreads();
    if (h == 0) {
        #pragma unroll
        for (int i = 0; i < 4; ++i)
            #pragma unroll
            for (int t = 0; t < 4; ++t)
                #pragma unroll
                for (int r = 0; r < 4; ++r) {
                    float v = acc[i][t][r] + red[((i * 4 + t) * 4 + r) * 64 + l];
                    int c = c0 + 16 * i + g * 4 + r;
                    size_t idx = ((size_t)(b * C_DIM + c)) * N_DIM + ncol[t];
                    out[idx] = v + x[idx];
                }
    }
}

// ============================================================
// launch
// ============================================================

extern "C" void kernel_launch(void* const* d_in, const int* in_sizes, int n_in,
                              void* d_out, int out_size, void* d_ws, size_t ws_size,
                              hipStream_t stream) {
    const float* x = (const float*)d_in[0];
    const float* W = (const float*)d_in[1];
    float* out = (float*)d_out;
    float* ws = (float*)d_ws;

    // ---- new-path ws layout (float offsets) ----
    const size_t o_s1p = 0,           // 40960
                 o_s2p = 40960,       // 40960
                 o_S   = 81920,       // 8192
                 o_idx = 90112,       // 8192
                 o_Eg  = 98304,       // 8192
                 o_Gg  = 106496,      // 8192
                 o_Jn  = 131076,      // 8192
                 o_fz  = 139268,      // 8192
                 o_hz  = 147460,      // 8192
                 o_tot = 221188,      // 81920
                 o_xT  = 303108,      // 1310720 (bf16 2*4096*320)
                 o_Tl  = 1613828,     // 2621440 (u32 2*4096*320)
                 o_end = 4235268;
    const size_t need_new = o_end * 4;

    // ---- mid-path (round-3) ws layout ----
    const size_t m_s1p = 0, m_s2p = 40960, m_s2 = 81920, m_Ek = 90112,
                 m_Gk = 98304, m_Fz = 106496, m_Hz = 114688, m_mx = 122880,
                 m_xb = 122888;
    const size_t need_mid = m_xb * 4 + (size_t)2 * C_DIM * N_DIM * 2;

    if (ws_size >= need_new) {
        float* s1p = ws + o_s1p;
        float* s2p = ws + o_s2p;
        float* Sg = ws + o_S;
        int*   idxg = (int*)(ws + o_idx);
        float* Eg = ws + o_Eg;
        float* Gg = ws + o_Gg;
        int*   JnA = (int*)(ws + o_Jn);
        float* fzA = ws + o_fz;
        float* hzA = ws + o_hz;
        float* tot = ws + o_tot;
        short* xT = (short*)(ws + o_xT);
        unsigned int* Tloc = (unsigned int*)(ws + o_Tl);

        k_pre<<<dim3(64, 5, 2), 256, 0, stream>>>(x, W, s1p, s2p, xT);
        k_rs <<<dim3(128, 2), 256, 0, stream>>>(s1p, Sg, idxg, Eg, Gg);
        k_pjz<<<192, 256, 0, stream>>>(xT, idxg, Eg, Gg, Sg, s2p,
                                       Tloc, tot, JnA, fzA, hzA);
        k_out<<<dim3(64, 5, 2), 256, 0, stream>>>(x, Tloc, tot, JnA, fzA, hzA, out);
    } else {
        float* s1p = ws + m_s1p;
        float* s2p = ws + m_s2p;
        float* s2  = ws + m_s2;
        float* Ekf = ws + m_Ek;
        float* Gkf = ws + m_Gk;
        float* Fz  = ws + m_Fz;
        float* Hz  = ws + m_Hz;
        float* s1max = ws + m_mx;
        short* xb = (short*)(ws + m_xb);
        k_s12 <<<dim3(64, 5, 2), 256, 0, stream>>>(x, W, s1p, s2p, xb);
        k_fold<<<2, 1024, 0, stream>>>(s1p, s2p, s2, Ekf, Gkf, s1max);
        k_z   <<<dim3(256, 2), 256, 0, stream>>>(s2, s1max, Ekf, Gkf, Fz, Hz);
        k_gemm<<<dim3(64, 5, 2), 128, 0, stream>>>(xb, x, Ekf, Gkf, Fz, Hz, out);
    }
}

// Round 15
// 47.240 us; speedup vs baseline: 6.9841x; 1.4821x over previous
//
#include <hip/hip_runtime.h>
#include <hip/hip_bf16.h>

#define C_DIM 320
#define N_DIM 4096
#define NEG 0.01f

typedef float f32x4 __attribute__((ext_vector_type(4)));
typedef float f32x2 __attribute__((ext_vector_type(2)));
typedef short bf16x8 __attribute__((ext_vector_type(8)));
typedef __bf16 bfv8 __attribute__((ext_vector_type(8)));

__device__ __forceinline__ float lrelu(float e) { return fmaxf(e, NEG * e); }

__device__ __forceinline__ unsigned short bf16bits(float v) {
    __hip_bfloat16 h = __float2bfloat16(v);
    return *(unsigned short*)&h;
}
__device__ __forceinline__ float bf16tof(unsigned short u) {
    unsigned int bits = ((unsigned int)u) << 16;
    return __builtin_bit_cast(float, bits);
}

__device__ __forceinline__ void gload_lds16(const void* g, void* l) {
    __builtin_amdgcn_global_load_lds(
        (const __attribute__((address_space(1))) void*)g,
        (__attribute__((address_space(3))) void*)l, 16, 0, 0);
}

// strict left-assoc fold of 5 c-group partials; IDENTICAL in k_rank/k_sct/k_pjz
// so sort keys and tie-breaks are byte-identical everywhere.
__device__ __forceinline__ float fold5(const float* __restrict__ p, int b, int i) {
    float v = p[((size_t)(b * 5 + 0)) * N_DIM + i];
    v += p[((size_t)(b * 5 + 1)) * N_DIM + i];
    v += p[((size_t)(b * 5 + 2)) * N_DIM + i];
    v += p[((size_t)(b * 5 + 3)) * N_DIM + i];
    v += p[((size_t)(b * 5 + 4)) * N_DIM + i];
    return v;
}

// ============================================================
// Sorted-prefix algorithm (no GEMM):
// out[c,n] = fz[n]*(SEtot[c] - SE_ex(Jn)[c]) + hz[n]*SG_ex(Jn)[c] + P[c,n]
// k sorted ascending by s1; Jn = lower_bound(S, -s2[n]).
// 5 dispatches: pre -> rank -> sct(32-block scatter) -> pjz(prefix || jz+scan) -> out
// ============================================================

// per (nb, cg, b): partial s1/s2 over 64 c's + bf16 transpose of 64n x 64c tile
__global__ __launch_bounds__(256) void k_pre(const float* __restrict__ x,
                                             const float* __restrict__ W,
                                             float* __restrict__ s1p,
                                             float* __restrict__ s2p,
                                             short* __restrict__ xT) {
    __shared__ float tile[64][65];
    __shared__ float r1[4][64], r2[4][64];
    const int b = blockIdx.z, cg = blockIdx.y, nb = blockIdx.x;
    const int nl = threadIdx.x & 63, cw = threadIdx.x >> 6;
    const int n0 = nb * 64, c0 = cg * 64;
    const int n = n0 + nl;
    float a1 = 0.f, a2 = 0.f;
    #pragma unroll
    for (int cc = 0; cc < 16; ++cc) {
        const int cl = cw * 16 + cc;
        const int c = c0 + cl;
        float v = x[((size_t)(b * C_DIM + c)) * N_DIM + n];
        a1 = fmaf(v, W[c], a1);
        a2 = fmaf(v, W[C_DIM + c], a2);
        tile[cl][nl] = v;
    }
    r1[cw][nl] = a1; r2[cw][nl] = a2;
    __syncthreads();
    const int half = nl >> 5;
    const int cp = nl & 31;
    #pragma unroll
    for (int rr = 0; rr < 8; ++rr) {
        const int nr = cw * 16 + rr * 2 + half;
        unsigned int pk = (unsigned int)bf16bits(tile[2 * cp][nr])
                        | ((unsigned int)bf16bits(tile[2 * cp + 1][nr]) << 16);
        *(unsigned int*)&xT[((size_t)b * N_DIM + n0 + nr) * C_DIM + c0 + 2 * cp] = pk;
    }
    if (threadIdx.x < 64) {
        float t1 = r1[0][nl] + r1[1][nl] + r1[2][nl] + r1[3][nl];
        float t2 = r2[0][nl] + r2[1][nl] + r2[2][nl] + r2[3][nl];
        s1p[((size_t)(b * 5 + cg)) * N_DIM + n] = t1;
        s2p[((size_t)(b * 5 + cg)) * N_DIM + n] = t2;
    }
}

// partial ranks: pcnt[b][chunk][k] = #{k' in chunk: s1[k'] < s1[k] (tie: k'<k)}
__global__ __launch_bounds__(256) void k_rank(const float* __restrict__ s1p,
                                              int* __restrict__ pcnt) {
    __shared__ float ch[512];
    const int chunk = blockIdx.x, kt = blockIdx.y, b = blockIdx.z;
    const int tid = threadIdx.x;
    const int kbase = chunk * 512;
    ch[tid] = fold5(s1p, b, kbase + tid);
    ch[tid + 256] = fold5(s1p, b, kbase + tid + 256);
    __syncthreads();
    const int k = kt * 256 + tid;
    const float v = fold5(s1p, b, k);
    int cnt = 0;
    #pragma unroll 8
    for (int i = 0; i < 512; ++i) {
        float sv = ch[i];
        int kc = kbase + i;
        cnt += (sv < v || (sv == v && kc < k)) ? 1 : 0;
    }
    pcnt[(b * 8 + chunk) * N_DIM + k] = cnt;
}

// 32-block parallel scatter: final rank = sum of 8 partials; write sorted arrays
// directly (scattered 4B writes, 8192 total, L2-absorbed). No LDS, no scan.
__global__ __launch_bounds__(256) void k_sct(const float* __restrict__ s1p,
                                             const int* __restrict__ pcnt,
                                             float* __restrict__ Sg,
                                             int* __restrict__ idxg,
                                             float* __restrict__ Eg,
                                             float* __restrict__ Gg) {
    const int b = blockIdx.y;
    const int k = blockIdx.x * 256 + threadIdx.x;
    int r = 0;
    #pragma unroll
    for (int c = 0; c < 8; ++c) r += pcnt[(b * 8 + c) * N_DIM + k];
    const float v = fold5(s1p, b, k);
    Sg[b * N_DIM + r] = v;
    idxg[b * N_DIM + r] = k;
    Eg[b * N_DIM + r] = __expf(v);
    Gg[b * N_DIM + r] = __expf(NEG * v);
}

// fused dispatch: blocks 0..159 = prefix (load-all-64 then compute, max MLP);
// blocks 160..191 = jz: stage sorted S/E/G, build EP/GP prefix in LDS (scan),
// then binary-search + Z for 256 rows each. Runs on CUs idle during prefix.
__global__ __launch_bounds__(256) void k_pjz(const short* __restrict__ xT,
                                             const int* __restrict__ idxg,
                                             const float* __restrict__ Eg,
                                             const float* __restrict__ Gg,
                                             const float* __restrict__ Sg,
                                             const float* __restrict__ s2p,
                                             unsigned int* __restrict__ Tloc,
                                             float* __restrict__ tot,
                                             int* __restrict__ JnA,
                                             float* __restrict__ fzA,
                                             float* __restrict__ hzA) {
    __shared__ float Sl[4096];
    __shared__ float Ei[4096], Gi[4096];
    __shared__ float wsE[4], wsG[4];
    const int w = threadIdx.x >> 6, l = threadIdx.x & 63;
    const int bx = blockIdx.x;
    if (bx < 160) {
        const int jt4 = bx & 15;
        const int cg = (bx >> 4) % 5;
        const int b = bx / 80;
        const int tile = jt4 * 4 + w;
        const int jbase = tile * 64;
        const int c = cg * 64 + l;
        const short* xTb = xT + (size_t)b * N_DIM * C_DIM;
        const float ej = Eg[b * N_DIM + jbase + l];
        const float gj = Gg[b * N_DIM + jbase + l];
        const int   ij = idxg[b * N_DIM + jbase + l];
        // phase 1: issue ALL 64 gathers (wave-limited occupancy; VGPRs free)
        unsigned short xv[64];
        #pragma unroll
        for (int j = 0; j < 64; ++j) {
            const int kidx = __shfl(ij, j);
            xv[j] = (unsigned short)xTb[(size_t)kidx * C_DIM + c];
        }
        // phase 2: prefix + packed stores, zero gather stalls
        float se = 0.f, sg = 0.f;
        #pragma unroll
        for (int j = 0; j < 64; ++j) {
            const float e = __shfl(ej, j);
            const float g = __shfl(gj, j);
            const float x0 = bf16tof(xv[j]);
            se = fmaf(x0, e, se);
            sg = fmaf(x0, g, sg);
            Tloc[((size_t)b * N_DIM + jbase + j) * C_DIM + c] =
                (unsigned int)bf16bits(se) | ((unsigned int)bf16bits(sg) << 16);
        }
        *(f32x2*)&tot[(((size_t)b * 64 + tile) * C_DIM + c) * 2] = (f32x2){se, sg};
    } else {
        const int jb = bx - 160;            // 0..31
        const int b = jb >> 4;
        const int nbase = (jb & 15) * 256;
        const int tid = threadIdx.x;
        for (int i = tid; i < 4096; i += 256) Sl[i] = Sg[b * N_DIM + i];
        float pe[16], pg[16];
        float se = 0.f, sgg = 0.f;
        #pragma unroll
        for (int q = 0; q < 4; ++q) {
            f32x4 e4 = *(const f32x4*)&Eg[b * N_DIM + tid * 16 + q * 4];
            f32x4 g4 = *(const f32x4*)&Gg[b * N_DIM + tid * 16 + q * 4];
            #pragma unroll
            for (int j = 0; j < 4; ++j) {
                se += e4[j];  pe[q * 4 + j] = se;
                sgg += g4[j]; pg[q * 4 + j] = sgg;
            }
        }
        float ie = se, ig = sgg;
        #pragma unroll
        for (int o = 1; o < 64; o <<= 1) {
            float ue = __shfl_up(ie, o);
            float ug = __shfl_up(ig, o);
            if (l >= o) { ie += ue; ig += ug; }
        }
        if (l == 63) { wsE[w] = ie; wsG[w] = ig; }
        __syncthreads();
        float oe = 0.f, og = 0.f;
        for (int ww = 0; ww < w; ++ww) { oe += wsE[ww]; og += wsG[ww]; }
        const float baseE = oe + ie - se, baseG = og + ig - sgg;
        #pragma unroll
        for (int q = 0; q < 16; ++q) {
            Ei[tid * 16 + q] = baseE + pe[q];
            Gi[tid * 16 + q] = baseG + pg[q];
        }
        __syncthreads();
        const float EPt = Ei[4095];
        const float smax = Sl[4095];
        const int n = nbase + tid;
        const float s2n = fold5(s2p, b, n);
        const float mn = lrelu(s2n + smax);
        const float F = __expf(s2n - mn), H = __expf(NEG * s2n - mn);
        const float t = -s2n;
        int lo = 0, hi = 4096;
        while (lo < hi) {
            int mid = (lo + hi) >> 1;
            if (Sl[mid] < t) lo = mid + 1; else hi = mid;
        }
        const float EPlo = lo ? Ei[lo - 1] : 0.f;
        const float GPlo = lo ? Gi[lo - 1] : 0.f;
        const float rz = 1.f / (F * (EPt - EPlo) + H * GPlo);
        JnA[b * N_DIM + n] = lo;
        fzA[b * N_DIM + n] = F * rz;
        hzA[b * N_DIM + n] = H * rz;
    }
}

// fused: per-block tile-offset scan + lookup + transpose + residual
__global__ __launch_bounds__(256) void k_out(const float* __restrict__ x,
                                             const unsigned int* __restrict__ Tloc,
                                             const float* __restrict__ tot,
                                             const int* __restrict__ JnA,
                                             const float* __restrict__ fzA,
                                             const float* __restrict__ hzA,
                                             float* __restrict__ out) {
    __shared__ float offl[65][64][2];
    __shared__ float wsum[4][64][2];
    __shared__ float tile[64][65];
    const int b = blockIdx.z, cg = blockIdx.y, n0 = blockIdx.x * 64;
    const int tid = threadIdx.x, w = tid >> 6, l = tid & 63;
    const int c0 = cg * 64;

    float ae = 0.f, ag = 0.f;
    #pragma unroll
    for (int i = 0; i < 16; ++i) {
        const int jt = w * 16 + i;
        offl[jt][l][0] = ae; offl[jt][l][1] = ag;
        f32x2 v = *(const f32x2*)&tot[(((size_t)b * 64 + jt) * C_DIM + c0 + l) * 2];
        ae += v[0]; ag += v[1];
    }
    wsum[w][l][0] = ae; wsum[w][l][1] = ag;
    __syncthreads();
    float be = 0.f, bg = 0.f;
    for (int ww = 0; ww < w; ++ww) { be += wsum[ww][l][0]; bg += wsum[ww][l][1]; }
    #pragma unroll
    for (int i = 0; i < 16; ++i) {
        const int jt = w * 16 + i;
        offl[jt][l][0] += be; offl[jt][l][1] += bg;
    }
    if (w == 3) { offl[64][l][0] = be + ae; offl[64][l][1] = bg + ag; }
    __syncthreads();

    const float gtE = offl[64][l][0];

    #pragma unroll
    for (int half = 0; half < 2; ++half) {
        unsigned int tvp[8];
        f32x2 ov[8];
        float fzs[8], hzs[8], msk[8];
        #pragma unroll
        for (int i = 0; i < 8; ++i) {
            const int n = n0 + w * 16 + half * 8 + i;
            const int Jn = JnA[b * N_DIM + n];
            fzs[i] = fzA[b * N_DIM + n];
            hzs[i] = hzA[b * N_DIM + n];
            const int jt = Jn >> 6, jl = Jn & 63;
            msk[i] = jl ? 1.f : 0.f;
            const int jrow = jl ? (Jn - 1) : 0;
            ov[i][0] = offl[jt][l][0];
            ov[i][1] = offl[jt][l][1];
            tvp[i] = Tloc[((size_t)b * N_DIM + jrow) * C_DIM + c0 + l];
        }
        #pragma unroll
        for (int i = 0; i < 8; ++i) {
            const float tvE = bf16tof((unsigned short)(tvp[i] & 0xFFFFu));
            const float tvG = bf16tof((unsigned short)(tvp[i] >> 16));
            const float se_ex = ov[i][0] + msk[i] * tvE;
            const float sg_ex = ov[i][1] + msk[i] * tvG;
            tile[l][w * 16 + half * 8 + i] = fzs[i] * (gtE - se_ex) + hzs[i] * sg_ex;
        }
    }
    __syncthreads();
    const int row = tid >> 2, nseg = (tid & 3) * 16;
    const size_t gidx = ((size_t)(b * C_DIM + c0 + row)) * N_DIM + n0 + nseg;
    #pragma unroll
    for (int i2 = 0; i2 < 16; i2 += 4) {
        f32x4 xv = *(const f32x4*)&x[gidx + i2];
        f32x4 o;
        #pragma unroll
        for (int q = 0; q < 4; ++q) o[q] = tile[row][nseg + i2 + q] + xv[q];
        *(f32x4*)&out[gidx + i2] = o;
    }
}

// ============================================================
// MID fallback: round-3 path (proven 75 us)
// ============================================================

__global__ __launch_bounds__(256) void k_s12(const float* __restrict__ x,
                                             const float* __restrict__ W,
                                             float* __restrict__ s1p,
                                             float* __restrict__ s2p,
                                             short* __restrict__ xb) {
    const int b = blockIdx.z, cb = blockIdx.y;
    const int nl = threadIdx.x & 63, cw = threadIdx.x >> 6;
    const int n = blockIdx.x * 64 + nl;
    const int cbase = cb * 64 + cw * 16;
    const float* px = x + ((size_t)b * C_DIM + cbase) * N_DIM + n;
    short* pxb = xb + ((size_t)b * C_DIM + cbase) * N_DIM + n;
    const float* w1 = W + cbase;
    const float* w2 = W + C_DIM + cbase;
    float a1 = 0.f, a2 = 0.f;
    #pragma unroll
    for (int cc = 0; cc < 16; ++cc) {
        float v = px[(size_t)cc * N_DIM];
        a1 = fmaf(v, w1[cc], a1);
        a2 = fmaf(v, w2[cc], a2);
        __hip_bfloat16 hv = __float2bfloat16(v);
        pxb[(size_t)cc * N_DIM] = *(short*)&hv;
    }
    __shared__ float r1[4][64], r2[4][64];
    r1[cw][nl] = a1; r2[cw][nl] = a2;
    __syncthreads();
    if (threadIdx.x < 64) {
        s1p[((size_t)b * 5 + cb) * N_DIM + n] = r1[0][nl] + r1[1][nl] + r1[2][nl] + r1[3][nl];
        s2p[((size_t)b * 5 + cb) * N_DIM + n] = r2[0][nl] + r2[1][nl] + r2[2][nl] + r2[3][nl];
    }
}

__global__ __launch_bounds__(1024) void k_fold(const float* __restrict__ s1p,
                                               const float* __restrict__ s2p,
                                               float* __restrict__ s2,
                                               float* __restrict__ Ekf,
                                               float* __restrict__ Gkf,
                                               float* __restrict__ s1max) {
    const int b = blockIdx.x, tid = threadIdx.x;
    __shared__ float md[1024];
    float mx = -3.4e38f;
    for (int n = tid; n < N_DIM; n += 1024) {
        float v1 = 0.f, v2 = 0.f;
        #pragma unroll
        for (int cb = 0; cb < 5; ++cb) {
            v1 += s1p[((size_t)b * 5 + cb) * N_DIM + n];
            v2 += s2p[((size_t)b * 5 + cb) * N_DIM + n];
        }
        s2[b * N_DIM + n] = v2;
        Ekf[b * N_DIM + n] = __expf(v1);
        Gkf[b * N_DIM + n] = __expf(NEG * v1);
        mx = fmaxf(mx, v1);
    }
    md[tid] = mx;
    __syncthreads();
    for (int s = 512; s > 0; s >>= 1) {
        if (tid < s) md[tid] = fmaxf(md[tid], md[tid + s]);
        __syncthreads();
    }
    if (tid == 0) s1max[b] = md[0];
}

__global__ __launch_bounds__(256) void k_z(const float* __restrict__ s2,
                                           const float* __restrict__ s1max,
                                           const float* __restrict__ Ekf,
                                           const float* __restrict__ Gkf,
                                           float* __restrict__ Fz,
                                           float* __restrict__ Hz) {
    __shared__ __align__(16) float Els[4096], Gls[4096];
    const int b = blockIdx.y, tid = threadIdx.x;
    const int w = tid >> 6, l = tid & 63;
    const float* Eb = Ekf + b * N_DIM;
    const float* Gb = Gkf + b * N_DIM;
    #pragma unroll
    for (int i = 0; i < 4; ++i) {
        int chn = i * 256 + tid;
        *(f32x4*)&Els[chn * 4] = *(const f32x4*)&Eb[chn * 4];
        *(f32x4*)&Gls[chn * 4] = *(const f32x4*)&Gb[chn * 4];
    }
    __syncthreads();
    float smax = s1max[b];
    #pragma unroll
    for (int rr = 0; rr < 4; ++rr) {
        int row = b * N_DIM + blockIdx.x * 16 + w * 4 + rr;
        float s2n = s2[row];
        float mn = lrelu(s2n + smax);
        float F = __expf(s2n - mn), H = __expf(NEG * s2n - mn);
        float sum = 0.f;
        #pragma unroll 4
        for (int i = 0; i < 16; ++i) {
            int k = i * 256 + l * 4;
            f32x4 e = *(const f32x4*)&Els[k];
            f32x4 gg = *(const f32x4*)&Gls[k];
            #pragma unroll
            for (int j = 0; j < 4; ++j) sum += fmaxf(e[j] * F, gg[j] * H);
        }
        #pragma unroll
        for (int off = 32; off > 0; off >>= 1) sum += __shfl_down(sum, off);
        if (l == 0) {
            float rz = 1.f / sum;
            Fz[row] = F * rz;
            Hz[row] = H * rz;
        }
    }
}

__global__ __launch_bounds__(128) void k_gemm(const short* __restrict__ xb,
                                              const float* __restrict__ x,
                                              const float* __restrict__ Ekf,
                                              const float* __restrict__ Gkf,
                                              const float* __restrict__ Fz,
                                              const float* __restrict__ Hz,
                                              float* __restrict__ out) {
    __shared__ __align__(16) short Asm[2][2][4096];
    __shared__ __align__(16) float EGs[2][2][256];

    const int b = blockIdx.z, c0 = blockIdx.y * 64, n0 = blockIdx.x * 64;
    const int tid = threadIdx.x;
    const int h = tid >> 6, l = tid & 63, lr = l & 15, g = l >> 4;
    const short* xbp = xb + (size_t)b * C_DIM * N_DIM + h * 2048;
    const float* Eb = Ekf + b * N_DIM + h * 2048;
    const float* Gb = Gkf + b * N_DIM + h * 2048;

    int ncol[4]; float fz[4], hz[4];
    #pragma unroll
    for (int t = 0; t < 4; ++t) {
        int n = n0 + t * 16 + lr;
        ncol[t] = n;
        fz[t] = Fz[b * N_DIM + n];
        hz[t] = Hz[b * N_DIM + n];
    }

    f32x4 acc[4][4];
    #pragma unroll
    for (int i = 0; i < 4; ++i)
        #pragma unroll
        for (int t = 0; t < 4; ++t) acc[i][t] = (f32x4){0.f, 0.f, 0.f, 0.f};

    auto stageA = [&](int buf, int it) {
        #pragma unroll
        for (int i = 0; i < 8; ++i) {
            int row = i * 8 + (l >> 3);
            int c8 = (l & 7) ^ (row & 7);
            gload_lds16(xbp + (size_t)(c0 + row) * N_DIM + it * 64 + c8 * 8,
                        &Asm[h][buf][i * 512]);
        }
    };
    auto stageEG = [&](int buf, int it) {
        int lm = l & 31;
        const float* p = (lm < 16) ? (Eb + it * 64 + lm * 4)
                                   : (Gb + it * 64 + (lm - 16) * 4);
        gload_lds16(p, &EGs[h][buf][0]);
    };

    stageA(0, 0); stageEG(0, 0);
    for (int it = 0; it < 32; ++it) {
        const int buf = it & 1;
        if (it < 31) {
            stageA(buf ^ 1, it + 1);
            stageEG(buf ^ 1, it + 1);
            asm volatile("s_waitcnt vmcnt(9)" ::: "memory");
        } else {
            asm volatile("s_waitcnt vmcnt(0)" ::: "memory");
        }
        __builtin_amdgcn_sched_barrier(0);
        #pragma unroll
        for (int s = 0; s < 2; ++s) {
            const int kk = s * 32 + g * 8;
            f32x4 e0 = *(const f32x4*)&EGs[h][buf][kk];
            f32x4 e1 = *(const f32x4*)&EGs[h][buf][kk + 4];
            f32x4 g0 = *(const f32x4*)&EGs[h][buf][64 + kk];
            f32x4 g1 = *(const f32x4*)&EGs[h][buf][64 + kk + 4];
            bf16x8 afr[4];
            #pragma unroll
            for (int i = 0; i < 4; ++i) {
                int row = 16 * i + lr;
                int idx = row * 64 + (((4 * s + g) ^ (row & 7)) * 8);
                afr[i] = *(const bf16x8*)&Asm[h][buf][idx];
            }
            bf16x8 bfr[4];
            #pragma unroll
            for (int t = 0; t < 4; ++t) {
                bfv8 qv;
                #pragma unroll
                for (int j = 0; j < 4; ++j) {
                    qv[j]     = (__bf16)fmaxf(e0[j] * fz[t], g0[j] * hz[t]);
                    qv[j + 4] = (__bf16)fmaxf(e1[j] * fz[t], g1[j] * hz[t]);
                }
                bfr[t] = __builtin_bit_cast(bf16x8, qv);
            }
            #pragma unroll
            for (int i = 0; i < 4; ++i)
                #pragma unroll
                for (int t = 0; t < 4; ++t)
                    acc[i][t] = __builtin_amdgcn_mfma_f32_16x16x32_bf16(
                        afr[i], bfr[t], acc[i][t], 0, 0, 0);
        }
    }

    __syncthreads();
    float* red = (float*)&Asm[0][0][0];
    if (h == 1) {
        #pragma unroll
        for (int i = 0; i < 4; ++i)
            #pragma unroll
            for (int t = 0; t < 4; ++t)
                #pragma unroll
                for (int r = 0; r < 4; ++r)
                    red[((i * 4 + t) * 4 + r) * 64 + l] = acc[i][t][r];
    }
    __syncthreads();
    if (h == 0) {
        #pragma unroll
        for (int i = 0; i < 4; ++i)
            #pragma unroll
            for (int t = 0; t < 4; ++t)
                #pragma unroll
                for (int r = 0; r < 4; ++r) {
                    float v = acc[i][t][r] + red[((i * 4 + t) * 4 + r) * 64 + l];
                    int c = c0 + 16 * i + g * 4 + r;
                    size_t idx = ((size_t)(b * C_DIM + c)) * N_DIM + ncol[t];
                    out[idx] = v + x[idx];
                }
    }
}

// ============================================================
// launch
// ============================================================

extern "C" void kernel_launch(void* const* d_in, const int* in_sizes, int n_in,
                              void* d_out, int out_size, void* d_ws, size_t ws_size,
                              hipStream_t stream) {
    const float* x = (const float*)d_in[0];
    const float* W = (const float*)d_in[1];
    float* out = (float*)d_out;
    float* ws = (float*)d_ws;

    // ---- new-path ws layout (float offsets) ----
    const size_t o_s1p = 0,           // 40960
                 o_s2p = 40960,       // 40960
                 o_S   = 81920,       // 8192
                 o_idx = 90112,       // 8192
                 o_Eg  = 98304,       // 8192
                 o_Gg  = 106496,      // 8192
                 o_Jn  = 131076,      // 8192
                 o_fz  = 139268,      // 8192
                 o_hz  = 147460,      // 8192
                 o_pc  = 155652,      // 65536
                 o_tot = 221188,      // 81920
                 o_xT  = 303108,      // 1310720 (bf16 2*4096*320)
                 o_Tl  = 1613828,     // 2621440 (u32 2*4096*320)
                 o_end = 4235268;
    const size_t need_new = o_end * 4;

    // ---- mid-path (round-3) ws layout ----
    const size_t m_s1p = 0, m_s2p = 40960, m_s2 = 81920, m_Ek = 90112,
                 m_Gk = 98304, m_Fz = 106496, m_Hz = 114688, m_mx = 122880,
                 m_xb = 122888;
    const size_t need_mid = m_xb * 4 + (size_t)2 * C_DIM * N_DIM * 2;

    if (ws_size >= need_new) {
        float* s1p = ws + o_s1p;
        float* s2p = ws + o_s2p;
        float* Sg = ws + o_S;
        int*   idxg = (int*)(ws + o_idx);
        float* Eg = ws + o_Eg;
        float* Gg = ws + o_Gg;
        int*   JnA = (int*)(ws + o_Jn);
        float* fzA = ws + o_fz;
        float* hzA = ws + o_hz;
        int*   pcnt = (int*)(ws + o_pc);
        float* tot = ws + o_tot;
        short* xT = (short*)(ws + o_xT);
        unsigned int* Tloc = (unsigned int*)(ws + o_Tl);

        k_pre <<<dim3(64, 5, 2), 256, 0, stream>>>(x, W, s1p, s2p, xT);
        k_rank<<<dim3(8, 16, 2), 256, 0, stream>>>(s1p, pcnt);
        k_sct <<<dim3(16, 2), 256, 0, stream>>>(s1p, pcnt, Sg, idxg, Eg, Gg);
        k_pjz <<<192, 256, 0, stream>>>(xT, idxg, Eg, Gg, Sg, s2p,
                                        Tloc, tot, JnA, fzA, hzA);
        k_out <<<dim3(64, 5, 2), 256, 0, stream>>>(x, Tloc, tot, JnA, fzA, hzA, out);
    } else {
        float* s1p = ws + m_s1p;
        float* s2p = ws + m_s2p;
        float* s2  = ws + m_s2;
        float* Ekf = ws + m_Ek;
        float* Gkf = ws + m_Gk;
        float* Fz  = ws + m_Fz;
        float* Hz  = ws + m_Hz;
        float* s1max = ws + m_mx;
        short* xb = (short*)(ws + m_xb);
        k_s12 <<<dim3(64, 5, 2), 256, 0, stream>>>(x, W, s1p, s2p, xb);
        k_fold<<<2, 1024, 0, stream>>>(s1p, s2p, s2, Ekf, Gkf, s1max);
        k_z   <<<dim3(256, 2), 256, 0, stream>>>(s2, s1max, Ekf, Gkf, Fz, Hz);
        k_gemm<<<dim3(64, 5, 2), 128, 0, stream>>>(xb, x, Ekf, Gkf, Fz, Hz, out);
    }
}